// Round 2
// baseline (366.307 us; speedup 1.0000x reference)
//
#include <hip/hip_runtime.h>
#include <math.h>

// Biquad lowpass over [B=256, T=160000] f32.
// Parallelization: IIR poles have |p| = sqrt(a2) ~ 0.577 -> state memory is
// effectively ~40 samples. Each thread owns an L-sample chunk and warm-starts
// W samples early from zero state; warm-up error ~0.577^W ~ 3e-12 at W=48.
// Single pass, memory-bound: ~360 MB traffic -> ~57 us roofline.

constexpr int T_LEN = 160000;
constexpr int B_ROWS = 256;
constexpr int L_CHUNK = 256;   // samples per thread (16B-aligned chunk starts)
constexpr int W_WARM = 48;     // warm-up samples (multiple of 4)
constexpr int CPR = T_LEN / L_CHUNK;  // 625 chunks per row

// One biquad step. y = b0*x + b1*x1 + b2*x2 - a1*y1 - a2*y2
#define BIQUAD_STEP(XIN, YOUT)                                              \
    do {                                                                    \
        float _x = (XIN);                                                   \
        float _t = b0 * _x + b1 * x1 + b2 * x2;                             \
        float _y = _t - a1 * y1 - a2 * y2;                                  \
        x2 = x1; x1 = _x; y2 = y1; y1 = _y;                                 \
        (YOUT) = _y;                                                        \
    } while (0)

__global__ __launch_bounds__(256) void biquad_kernel(
        const float* __restrict__ x, float* __restrict__ y,
        float b0, float b1, float b2, float a1, float a2) {
    int gid = blockIdx.x * blockDim.x + threadIdx.x;
    int row = gid / CPR;
    int c   = gid - row * CPR;

    const float* __restrict__ xr = x + (size_t)row * T_LEN;
    float* __restrict__ yr       = y + (size_t)row * T_LEN;
    int s = c * L_CHUNK;

    float x1 = 0.f, x2 = 0.f, y1 = 0.f, y2 = 0.f;

    // Warm-up: run W samples before the chunk to converge the state.
    // c == 0 starts exactly at the row start with true zero state (exact).
    if (c > 0) {
        const float4* wp = reinterpret_cast<const float4*>(xr + s - W_WARM);
        #pragma unroll
        for (int i = 0; i < W_WARM / 4; ++i) {
            float4 xv = wp[i];
            float dump;
            BIQUAD_STEP(xv.x, dump);
            BIQUAD_STEP(xv.y, dump);
            BIQUAD_STEP(xv.z, dump);
            BIQUAD_STEP(xv.w, dump);
            (void)dump;
        }
    }

    // Main chunk: float4 in / float4 out.
    const float4* __restrict__ xp = reinterpret_cast<const float4*>(xr + s);
    float4* __restrict__ yp       = reinterpret_cast<float4*>(yr + s);
    #pragma unroll 4
    for (int i = 0; i < L_CHUNK / 4; ++i) {
        float4 xv = xp[i];
        float4 yv;
        BIQUAD_STEP(xv.x, yv.x);
        BIQUAD_STEP(xv.y, yv.y);
        BIQUAD_STEP(xv.z, yv.z);
        BIQUAD_STEP(xv.w, yv.w);
        yp[i] = yv;
    }
}

extern "C" void kernel_launch(void* const* d_in, const int* in_sizes, int n_in,
                              void* d_out, int out_size, void* d_ws, size_t ws_size,
                              hipStream_t stream) {
    const float* x = (const float*)d_in[0];
    float* y = (float*)d_out;

    // Coefficients: double precision math, then cast to f32 (matches
    // numpy float64 computation + np.float32 cast in the reference).
    const double SR = 32000.0, CUT = 4000.0, Q = 0.707;
    double w0 = 2.0 * M_PI * CUT / SR;
    double alpha = sin(w0) / (2.0 * Q);
    double cosw = cos(w0);
    double b0d = (1.0 - cosw) / 2.0;
    double b1d = 1.0 - cosw;
    double b2d = b0d;
    double a0d = 1.0 + alpha;
    double a1d = -2.0 * cosw;
    double a2d = 1.0 - alpha;
    float b0 = (float)(b0d / a0d);
    float b1 = (float)(b1d / a0d);
    float b2 = (float)(b2d / a0d);
    float a1 = (float)(a1d / a0d);
    float a2 = (float)(a2d / a0d);

    int total_threads = B_ROWS * CPR;        // 160000
    int block = 256;
    int grid = (total_threads + block - 1) / block;  // 625
    biquad_kernel<<<grid, block, 0, stream>>>(x, y, b0, b1, b2, a1, a2);
}

// Round 3
// 276.548 us; speedup vs baseline: 1.3246x; 1.3246x over previous
//
#include <hip/hip_runtime.h>
#include <math.h>

// Biquad lowpass over [B=256, T=160000] f32 — LDS-staged chunked scan.
//
// R2 post-mortem: direct strided version hit 2.4 TB/s (30% peak) with 1.48x
// write amplification (WRITE_SIZE 243 MB vs 164 ideal) from 16B-per-lane
// stores at 1KB stride, and 64-segment load instructions. Fix: stage a
// contiguous block tile through LDS so ALL global traffic is coalesced
// float4; the serial-per-chunk IIR walks LDS instead (stride 33 = padded,
// bank-conflict-free). Warm-up reads the previous chunk from LDS (no extra
// HBM traffic). |pole| = 0.577 -> W=32 warm-up leaves ~2e-8 state error vs
// the 5.6e-2 threshold (observed f32-recurrence noise floor is ~8e-3).

constexpr int T_LEN   = 160000;
constexpr int B_ROWS  = 256;
constexpr int L       = 32;               // samples per thread-chunk
constexpr int W       = 32;               // warm-up samples (== L: prev chunk)
constexpr int THREADS = 256;
constexpr int STRIDE  = L + 1;            // 33 floats -> conflict-free LDS walk
constexpr int CPR     = T_LEN / L;        // 5000 chunks per row
constexpr int TILE_F  = THREADS * L;      // 8192 floats per block tile
constexpr int F4_PT   = TILE_F / 4 / THREADS;  // 8 float4 per thread staging

// y = b0*x + b1*x1 + b2*x2 - a1*y1 - a2*y2
#define BIQUAD_STEP(XIN, YOUT)                                              \
    do {                                                                    \
        float _x = (XIN);                                                   \
        float _t = b0 * _x + b1 * x1 + b2 * x2;                             \
        float _y = _t - a1 * y1 - a2 * y2;                                  \
        x2 = x1; x1 = _x; y2 = y1; y1 = _y;                                 \
        (YOUT) = _y;                                                        \
    } while (0)

__global__ __launch_bounds__(THREADS) void biquad_lds_kernel(
        const float* __restrict__ x, float* __restrict__ y,
        float b0, float b1, float b2, float a1, float a2) {
    __shared__ float lds[THREADS * STRIDE];   // 33792 B -> 4 blocks/CU

    const int tid = threadIdx.x;
    const long long tile_f = (long long)blockIdx.x * TILE_F;
    const float4* __restrict__ xg4 = reinterpret_cast<const float4*>(x + tile_f);
    float4* __restrict__ yg4       = reinterpret_cast<float4*>(y + tile_f);

    // ---- stage: global (coalesced float4) -> LDS (padded chunk-major) ----
    #pragma unroll
    for (int w = 0; w < F4_PT; ++w) {
        int e4 = tid + w * THREADS;           // coalesced float4 index in tile
        float4 v = xg4[e4];
        int cc = e4 >> 3;                     // owning chunk (8 float4 / chunk)
        int jj = e4 & 7;
        int fb = cc * STRIDE + (jj << 2);
        lds[fb]   = v.x; lds[fb+1] = v.y;     // compiler fuses to ds_write2_b32
        lds[fb+2] = v.z; lds[fb+3] = v.w;
    }
    __syncthreads();

    const long long g = (long long)blockIdx.x * THREADS + tid;  // global chunk
    const int pos = (int)(g % CPR);           // chunk position within its row

    float x1 = 0.f, x2 = 0.f, y1 = 0.f, y2 = 0.f;
    float dump;

    // ---- warm-up: converge state on the previous W samples ----
    // pos == 0 -> row start, true zero state (exact). Reads only x values;
    // barrier below keeps them ordered before any in-place y overwrite.
    if (pos != 0) {
        if (tid > 0) {
            const int base = (tid - 1) * STRIDE;   // prev chunk, in this tile
            #pragma unroll
            for (int i = 0; i < W; ++i) {
                BIQUAD_STEP(lds[base + i], dump);
            }
        } else {
            // first chunk of the tile: predecessor lives in the previous tile
            const float4* wp = reinterpret_cast<const float4*>(x + g * L - W);
            #pragma unroll
            for (int i = 0; i < W / 4; ++i) {
                float4 v = wp[i];
                BIQUAD_STEP(v.x, dump);
                BIQUAD_STEP(v.y, dump);
                BIQUAD_STEP(v.z, dump);
                BIQUAD_STEP(v.w, dump);
            }
        }
        (void)dump;
    }
    __syncthreads();   // all warm-up reads of x done before y overwrites

    // ---- main: filter own chunk in place in LDS ----
    {
        const int base = tid * STRIDE;
        #pragma unroll
        for (int i = 0; i < L; ++i) {
            float yo;
            BIQUAD_STEP(lds[base + i], yo);
            lds[base + i] = yo;
        }
    }
    __syncthreads();

    // ---- store: LDS (padded chunk-major) -> global (coalesced float4) ----
    #pragma unroll
    for (int w = 0; w < F4_PT; ++w) {
        int e4 = tid + w * THREADS;
        int cc = e4 >> 3;
        int jj = e4 & 7;
        int fb = cc * STRIDE + (jj << 2);
        float4 v;
        v.x = lds[fb];   v.y = lds[fb+1];
        v.z = lds[fb+2]; v.w = lds[fb+3];
        yg4[e4] = v;
    }
}

extern "C" void kernel_launch(void* const* d_in, const int* in_sizes, int n_in,
                              void* d_out, int out_size, void* d_ws, size_t ws_size,
                              hipStream_t stream) {
    const float* x = (const float*)d_in[0];
    float* y = (float*)d_out;

    const double SR = 32000.0, CUT = 4000.0, Q = 0.707;
    double w0 = 2.0 * M_PI * CUT / SR;
    double alpha = sin(w0) / (2.0 * Q);
    double cosw = cos(w0);
    double b0d = (1.0 - cosw) / 2.0;
    double b1d = 1.0 - cosw;
    double b2d = b0d;
    double a0d = 1.0 + alpha;
    double a1d = -2.0 * cosw;
    double a2d = 1.0 - alpha;
    float b0 = (float)(b0d / a0d);
    float b1 = (float)(b1d / a0d);
    float b2 = (float)(b2d / a0d);
    float a1 = (float)(a1d / a0d);
    float a2 = (float)(a2d / a0d);

    int total_f = B_ROWS * T_LEN;            // 40,960,000 floats
    int grid = total_f / TILE_F;             // 5000 blocks, exact
    biquad_lds_kernel<<<grid, THREADS, 0, stream>>>(x, y, b0, b1, b2, a1, a2);
}